// Round 1
// baseline (232.254 us; speedup 1.0000x reference)
//
#include <hip/hip_runtime.h>

#define NHEADS 16
#define HDIM   64
#define HID    1024
#define BATCH  8
#define LW     512
#define LE     64
#define SEQ    576            // LW + LE
#define MTOT   (BATCH * SEQ)  // 4608

typedef unsigned short u16;
typedef __bf16 bf16x8 __attribute__((ext_vector_type(8)));
typedef float  f32x4  __attribute__((ext_vector_type(4)));

__device__ __forceinline__ u16 f2bf(float f) {
  union { float f; unsigned int i; } x;
  x.f = f;
  unsigned int u = x.i;
  unsigned int r = (u + 0x7FFFu + ((u >> 16) & 1u)) >> 16;
  return (u16)r;
}
__device__ __forceinline__ unsigned int pk2(float a, float b) {
  return (unsigned int)f2bf(a) | ((unsigned int)f2bf(b) << 16);
}

// async global->LDS, 16B/lane. Per-lane LDS ptr must equal wave base + lane*16.
__device__ __forceinline__ void gload16(const u16* g, u16* l) {
  __builtin_amdgcn_global_load_lds(
      (const __attribute__((address_space(1))) void*)g,
      (__attribute__((address_space(3))) void*)l, 16, 0, 0);
}

// ---------------------------------------------------------------------------
// Kernel 0: prep = weight transpose+cvt (blocks 0..4095) | x gather+cvt (rest)
// ---------------------------------------------------------------------------
__global__ __launch_bounds__(256) void prep_k(
    const float* __restrict__ w0, const float* __restrict__ w1,
    const float* __restrict__ w2, const float* __restrict__ w3,
    u16* __restrict__ wt,
    const float* __restrict__ word, const float* __restrict__ ent,
    u16* __restrict__ xb)
{
  const int bid = blockIdx.x, tid = threadIdx.x;
  if (bid < 4096) {
    __shared__ u16 tile[32][33];
    const int z = bid >> 10, rem = bid & 1023;
    const int bx = rem & 31, by = rem >> 5;
    const float* src = (z == 0) ? w0 : (z == 1) ? w1 : (z == 2) ? w2 : w3;
    u16* dst = wt + (size_t)z * HID * HID;
    const int tx = tid & 31, ty = tid >> 5;
    const int nx = bx * 32, ky = by * 32;
#pragma unroll
    for (int j = 0; j < 4; ++j)
      tile[ty * 4 + j][tx] = f2bf(src[(size_t)(ky + ty * 4 + j) * HID + nx + tx]);
    __syncthreads();
#pragma unroll
    for (int j = 0; j < 4; ++j)
      dst[(size_t)(nx + ty * 4 + j) * HID + ky + tx] = tile[tx][ty * 4 + j];
  } else {
    const int row = bid - 4096;
    const int bb = row / SEQ, ss = row - bb * SEQ;
    const float* src = (ss < LW) ? word + (size_t)(bb * LW + ss) * HID
                                 : ent  + (size_t)(bb * LE + (ss - LW)) * HID;
    float4 v = *(const float4*)(src + tid * 4);
    ushort4 o;
    o.x = f2bf(v.x); o.y = f2bf(v.y); o.z = f2bf(v.z); o.w = f2bf(v.w);
    *(ushort4*)(xb + (size_t)row * HID + tid * 4) = o;
  }
}

// ---------------------------------------------------------------------------
// Kernel 1: fused QKV GEMM — R11: 256x256 tile, BK=64, 8-phase counted-vmcnt
// schedule (T3+T4) with setprio (T5) on top of the existing XOR swizzle (T2).
// 512 threads = 8 waves (2M x 4N), per-wave 128x64, LDS 128 KiB dbuf.
// Chunk = 64 rows x 64 k (8 KB, 1 gload16/thread). A = 4 chunks, B = 4 chunks
// per K-step. Issue schedule (WAR-safe at chunk granularity):
//   ph1: B23(s+1)   [other buffer; B23(s-1) read done at (s-1).2]
//   ph2: A02(s+2)   [same buffer; A02(s) read done at ph1]
//   ph3: B01(s+2)   [B(s) reads done at ph2 — B frags held in regs for ph3/4]
//   ph4: A13(s+2)   [A13(s) read done at ph3]
// Steady state: 3 chunk-pairs = vmcnt(6), waited once per K-step at ph4.
// Epilogues identical to R9/R10 (per-wave 64x64 group x2): layouts unchanged.
// ---------------------------------------------------------------------------
__device__ __forceinline__ void qkv_kstep(
    u16* sh, const u16* asrc, const u16* bsrc, const int s, const int bo,
    const bool g1, const bool g2, const bool vlast, const int which,
    const int wm, const int wn, const int lr, const int quad, const int fsw,
    const int tid, f32x4 (&acc)[8][4])
{
  u16* As = sh + bo;            // A: 256 x 64, chunk c at c*4096
  u16* Bs = sh + bo + 16384;    // B: 256 x 64
  const int obo = 32768 - bo;   // other buffer
  bf16x8 afa[4][2], afb[4][2], bfr[4][2];

  // ---- phase 1: read A lo-half + B(ni 0,1); stage B23(s+1) ----
#pragma unroll
  for (int mi = 0; mi < 4; ++mi)
#pragma unroll
    for (int ks = 0; ks < 2; ++ks)
      afa[mi][ks] = *(const bf16x8*)(&As[(wm + mi * 16 + lr) * 64 + (((ks * 4 + quad) ^ fsw) * 8)]);
#pragma unroll
  for (int ni = 0; ni < 2; ++ni)
#pragma unroll
    for (int ks = 0; ks < 2; ++ks)
      bfr[ni][ks] = *(const bf16x8*)(&Bs[(wn + ni * 16 + lr) * 64 + (((ks * 4 + quad) ^ fsw) * 8)]);
  if (g1) {
    gload16(bsrc + (size_t)2 * 64 * HID + (s + 1) * 64, sh + obo + 16384 + 2 * 4096 + tid * 8);
    gload16(bsrc + (size_t)3 * 64 * HID + (s + 1) * 64, sh + obo + 16384 + 3 * 4096 + tid * 8);
  }
  asm volatile("s_waitcnt lgkmcnt(8)" ::: "memory");
  __builtin_amdgcn_s_barrier();
  asm volatile("s_waitcnt lgkmcnt(0)" ::: "memory");
  __builtin_amdgcn_sched_barrier(0);
  __builtin_amdgcn_s_setprio(1);
  if (which < 2) {
#pragma unroll
    for (int mi = 0; mi < 4; ++mi)
#pragma unroll
      for (int ni = 0; ni < 2; ++ni)
#pragma unroll
        for (int ks = 0; ks < 2; ++ks)
          acc[mi][ni] = __builtin_amdgcn_mfma_f32_16x16x32_bf16(bfr[ni][ks], afa[mi][ks], acc[mi][ni], 0, 0, 0);
  } else {
#pragma unroll
    for (int mi = 0; mi < 4; ++mi)
#pragma unroll
      for (int ni = 0; ni < 2; ++ni)
#pragma unroll
        for (int ks = 0; ks < 2; ++ks)
          acc[mi][ni] = __builtin_amdgcn_mfma_f32_16x16x32_bf16(afa[mi][ks], bfr[ni][ks], acc[mi][ni], 0, 0, 0);
  }
  __builtin_amdgcn_s_setprio(0);
  __builtin_amdgcn_s_barrier();

  // ---- phase 2: read B(ni 2,3); stage A02(s+2) ----
#pragma unroll
  for (int ni = 2; ni < 4; ++ni)
#pragma unroll
    for (int ks = 0; ks < 2; ++ks)
      bfr[ni][ks] = *(const bf16x8*)(&Bs[(wn + ni * 16 + lr) * 64 + (((ks * 4 + quad) ^ fsw) * 8)]);
  if (g2) {
    gload16(asrc + (size_t)0 * 64 * HID + (s + 2) * 64, sh + bo + 0 * 4096 + tid * 8);
    gload16(asrc + (size_t)2 * 64 * HID + (s + 2) * 64, sh + bo + 2 * 4096 + tid * 8);
  }
  __builtin_amdgcn_s_barrier();
  asm volatile("s_waitcnt lgkmcnt(0)" ::: "memory");
  __builtin_amdgcn_sched_barrier(0);
  __builtin_amdgcn_s_setprio(1);
  if (which < 2) {
#pragma unroll
    for (int mi = 0; mi < 4; ++mi)
#pragma unroll
      for (int ni = 2; ni < 4; ++ni)
#pragma unroll
        for (int ks = 0; ks < 2; ++ks)
          acc[mi][ni] = __builtin_amdgcn_mfma_f32_16x16x32_bf16(bfr[ni][ks], afa[mi][ks], acc[mi][ni], 0, 0, 0);
  } else {
#pragma unroll
    for (int mi = 0; mi < 4; ++mi)
#pragma unroll
      for (int ni = 2; ni < 4; ++ni)
#pragma unroll
        for (int ks = 0; ks < 2; ++ks)
          acc[mi][ni] = __builtin_amdgcn_mfma_f32_16x16x32_bf16(afa[mi][ks], bfr[ni][ks], acc[mi][ni], 0, 0, 0);
  }
  __builtin_amdgcn_s_setprio(0);
  __builtin_amdgcn_s_barrier();

  // ---- phase 3: read A hi-half; stage B01(s+2) ----
#pragma unroll
  for (int mi = 0; mi < 4; ++mi)
#pragma unroll
    for (int ks = 0; ks < 2; ++ks)
      afb[mi][ks] = *(const bf16x8*)(&As[(wm + 64 + mi * 16 + lr) * 64 + (((ks * 4 + quad) ^ fsw) * 8)]);
  if (g2) {
    gload16(bsrc + (size_t)0 * 64 * HID + (s + 2) * 64, sh + bo + 16384 + 0 * 4096 + tid * 8);
    gload16(bsrc + (size_t)1 * 64 * HID + (s + 2) * 64, sh + bo + 16384 + 1 * 4096 + tid * 8);
  }
  __builtin_amdgcn_s_barrier();
  asm volatile("s_waitcnt lgkmcnt(0)" ::: "memory");
  __builtin_amdgcn_sched_barrier(0);
  __builtin_amdgcn_s_setprio(1);
  if (which < 2) {
#pragma unroll
    for (int mi = 0; mi < 4; ++mi)
#pragma unroll
      for (int ni = 0; ni < 2; ++ni)
#pragma unroll
        for (int ks = 0; ks < 2; ++ks)
          acc[4 + mi][ni] = __builtin_amdgcn_mfma_f32_16x16x32_bf16(bfr[ni][ks], afb[mi][ks], acc[4 + mi][ni], 0, 0, 0);
  } else {
#pragma unroll
    for (int mi = 0; mi < 4; ++mi)
#pragma unroll
      for (int ni = 0; ni < 2; ++ni)
#pragma unroll
        for (int ks = 0; ks < 2; ++ks)
          acc[4 + mi][ni] = __builtin_amdgcn_mfma_f32_16x16x32_bf16(afb[mi][ks], bfr[ni][ks], acc[4 + mi][ni], 0, 0, 0);
  }
  __builtin_amdgcn_s_setprio(0);
  __builtin_amdgcn_s_barrier();

  // ---- phase 4: stage A13(s+2); MFMA hi x ni23; counted vmcnt ----
  if (g2) {
    gload16(asrc + (size_t)1 * 64 * HID + (s + 2) * 64, sh + bo + 1 * 4096 + tid * 8);
    gload16(asrc + (size_t)3 * 64 * HID + (s + 2) * 64, sh + bo + 3 * 4096 + tid * 8);
  }
  __builtin_amdgcn_s_barrier();
  __builtin_amdgcn_sched_barrier(0);
  __builtin_amdgcn_s_setprio(1);
  if (which < 2) {
#pragma unroll
    for (int mi = 0; mi < 4; ++mi)
#pragma unroll
      for (int ni = 2; ni < 4; ++ni)
#pragma unroll
        for (int ks = 0; ks < 2; ++ks)
          acc[4 + mi][ni] = __builtin_amdgcn_mfma_f32_16x16x32_bf16(bfr[ni][ks], afb[mi][ks], acc[4 + mi][ni], 0, 0, 0);
  } else {
#pragma unroll
    for (int mi = 0; mi < 4; ++mi)
#pragma unroll
      for (int ni = 2; ni < 4; ++ni)
#pragma unroll
        for (int ks = 0; ks < 2; ++ks)
          acc[4 + mi][ni] = __builtin_amdgcn_mfma_f32_16x16x32_bf16(afb[mi][ks], bfr[ni][ks], acc[4 + mi][ni], 0, 0, 0);
  }
  __builtin_amdgcn_s_setprio(0);
  if (!vlast) asm volatile("s_waitcnt vmcnt(6)" ::: "memory");
  else        asm volatile("s_waitcnt vmcnt(0)" ::: "memory");
  __builtin_amdgcn_s_barrier();
}

__global__ __launch_bounds__(512, 2) void qkv_gemm_k(
    const u16* __restrict__ xb, const u16* __restrict__ wt,
    const float* __restrict__ bq, const float* __restrict__ bk, const float* __restrict__ bv,
    u16* __restrict__ q_ws, u16* __restrict__ k_ws, u16* __restrict__ v_ws)
{
  __shared__ u16 sh[65536];            // 128 KiB: 2 x (A 256x64 | B 256x64)
  const int which = blockIdx.z;
  const u16* W = wt + (size_t)which * HID * HID;
  const float* bias = (which == 0) ? bq : (which == 1) ? bk : bv;
  const int m0 = blockIdx.x * 256, n0 = blockIdx.y * 256;
  const int tid = threadIdx.x, lane = tid & 63, wv = tid >> 6;
  const int lr = lane & 15, quad = lane >> 4;
  const int wm = (wv >> 2) * 128, wn = (wv & 3) * 64;   // per-wave 128x64
  const int fsw = lr & 7;

  // staging: all 512 threads cover one 64x64 chunk (srow = row, goff = swizzled k)
  const int srow = tid >> 3;
  const int goff = ((tid & 7) ^ (srow & 7)) * 8;
  const u16* asrc = xb + (size_t)(m0 + srow) * HID + goff;
  const u16* bsrc = W  + (size_t)(n0 + srow) * HID + goff;

  // prologue: K0 full (8 chunks), then {A02,B01,A13}(K1) (6 chunks)
  gload16(asrc + (size_t)0 * 64 * HID, sh + 0 * 4096 + tid * 8);
  gload16(asrc + (size_t)1 * 64 * HID, sh + 1 * 4096 + tid * 8);
  gload16(asrc + (size_t)2 * 64 * HID, sh + 2 * 4096 + tid * 8);
  gload16(asrc + (size_t)3 * 64 * HID, sh + 3 * 4096 + tid * 8);
  gload16(bsrc + (size_t)0 * 64 * HID, sh + 16384 + 0 * 4096 + tid * 8);
  gload16(bsrc + (size_t)1 * 64 * HID, sh + 16384 + 1 * 4096 + tid * 8);
  gload16(bsrc + (size_t)2 * 64 * HID, sh + 16384 + 2 * 4096 + tid * 8);
  gload16(bsrc + (size_t)3 * 64 * HID, sh + 16384 + 3 * 4096 + tid * 8);
  gload16(asrc + (size_t)0 * 64 * HID + 64, sh + 32768 + 0 * 4096 + tid * 8);
  gload16(asrc + (size_t)2 * 64 * HID + 64, sh + 32768 + 2 * 4096 + tid * 8);
  gload16(bsrc + (size_t)0 * 64 * HID + 64, sh + 32768 + 16384 + 0 * 4096 + tid * 8);
  gload16(bsrc + (size_t)1 * 64 * HID + 64, sh + 32768 + 16384 + 1 * 4096 + tid * 8);
  gload16(asrc + (size_t)1 * 64 * HID + 64, sh + 32768 + 1 * 4096 + tid * 8);
  gload16(asrc + (size_t)3 * 64 * HID + 64, sh + 32768 + 3 * 4096 + tid * 8);
  asm volatile("s_waitcnt vmcnt(6)" ::: "memory");
  __builtin_amdgcn_s_barrier();

  const f32x4 fz = {0.f, 0.f, 0.f, 0.f};
  f32x4 acc[8][4];
#pragma unroll
  for (int a = 0; a < 8; ++a)
#pragma unroll
    for (int b = 0; b < 4; ++b) acc[a][b] = fz;

  for (int s = 0; s < 16; s += 2) {
    qkv_kstep(sh, asrc, bsrc, s,     0,     true,   s < 14, s >= 14, which,
              wm, wn, lr, quad, fsw, tid, acc);
    qkv_kstep(sh, asrc, bsrc, s + 1, 32768, s < 14, s < 13, s >= 13, which,
              wm, wn, lr, quad, fsw, tid, acc);
  }

  // epilogue: per-wave 64x64 group x2, LDS transpose with packed b64 writes
  u16* tb = sh + wv * (64 * 68);
  const int head = (n0 + wn) >> 6;

  if (which < 2) {
    // acc[mi][ni]: d = ni*16+quad*4+r, token = mi*16+lr
    float4 bias4[4];
#pragma unroll
    for (int ni = 0; ni < 4; ++ni)
      bias4[ni] = *(const float4*)(bias + n0 + wn + ni * 16 + quad * 4);
    u16* qk = (which == 0 ? q_ws : k_ws);
#pragma unroll
    for (int g = 0; g < 2; ++g) {
      const int mbase = m0 + wm + g * 64;          // 64-aligned; never crosses batch
      const int bb = mbase / SEQ;
      const int ssb = mbase - bb * SEQ;
#pragma unroll
      for (int mi = 0; mi < 4; ++mi)
#pragma unroll
        for (int ni = 0; ni < 4; ++ni) {
          const f32x4 a = acc[g * 4 + mi][ni];
          uint2 w2v;
          w2v.x = pk2(a[0] + bias4[ni].x, a[1] + bias4[ni].y);
          w2v.y = pk2(a[2] + bias4[ni].z, a[3] + bias4[ni].w);
          *(uint2*)(&tb[(mi * 16 + lr) * 68 + ni * 16 + quad * 4]) = w2v;
        }
      u16* drow = qk + ((size_t)(bb * NHEADS + head) * SEQ + ssb) * HDIM;
#pragma unroll
      for (int i = 0; i < 8; ++i) {
        int rrow = i * 8 + (lane >> 3);
        int seg = lane & 7;
        bf16x8 v8 = *(const bf16x8*)(&tb[rrow * 68 + seg * 8]);
        *(bf16x8*)(drow + (size_t)rrow * HDIM + seg * 8) = v8;
      }
    }
  } else {
    // acc[mi][ni]: d = ni*16+lr, sigma(token) r-consecutive
    float bcol[4];
#pragma unroll
    for (int ni = 0; ni < 4; ++ni) bcol[ni] = bias[n0 + wn + ni * 16 + lr];
#pragma unroll
    for (int g = 0; g < 2; ++g) {
      const int mbase = m0 + wm + g * 64;
      const int bb = mbase / SEQ;
      const int ssb = mbase - bb * SEQ;
#pragma unroll
      for (int mi = 0; mi < 4; ++mi)
#pragma unroll
        for (int ni = 0; ni < 4; ++ni) {
          const f32x4 a = acc[g * 4 + mi][ni];
          uint2 w2v;
          w2v.x = pk2(a[0] + bcol[ni], a[1] + bcol[ni]);
          w2v.y = pk2(a[2] + bcol[ni], a[3] + bcol[ni]);
          *(uint2*)(&tb[(ni * 16 + lr) * 68 + (mi >> 1) * 32 + quad * 8 + (mi & 1) * 4]) = w2v;
        }
      u16* dcol = v_ws + ((size_t)(bb * NHEADS + head) * HDIM) * SEQ + ssb;
#pragma unroll
      for (int i = 0; i < 8; ++i) {
        int d = i * 8 + (lane >> 3);
        int seg = lane & 7;
        bf16x8 v8 = *(const bf16x8*)(&tb[d * 68 + seg * 8]);
        *(bf16x8*)(dcol + (size_t)d * SEQ + seg * 8) = v8;
      }
    }
  }
}

// ---------------------------------------------------------------------------
// Kernel 2: flash attention (R10-measured: single-buffer staging, 18.7 KB LDS)
// ---------------------------------------------------------------------------
__global__ __launch_bounds__(256) void attn_k(
    const u16* __restrict__ q_ws, const u16* __restrict__ k_ws,
    const u16* __restrict__ v_ws, const float* __restrict__ mask,
    u16* __restrict__ ctxh)
{
  __shared__ u16 Ks[4096];
  __shared__ u16 Vs[4096];
  __shared__ float ms[576];
  const int bhx = blockIdx.x, qt = blockIdx.y;
  const int b = bhx >> 4, h = bhx & 15;
  const int tid = threadIdx.x, lane = tid & 63, wv = tid >> 6;
  const int lr = lane & 15, quad = lane >> 4;
  const int q0 = qt * 64 + wv * 16;
  const u16* kbh = k_ws + (size_t)bhx * SEQ * HDIM;
  const u16* vbh = v_ws + (size_t)bhx * HDIM * SEQ;
  const u16* qp  = q_ws + ((size_t)bhx * SEQ + q0) * HDIM;
  const float* mrow = mask + b * SEQ;

  if (tid < 144) *(float4*)(&ms[tid * 4]) = *(const float4*)(mrow + tid * 4);

  const int subrow = lane >> 3;
  const int gsw = (lane & 7) ^ subrow;

  bf16x8 qf[2];
  qf[0] = *(const bf16x8*)(qp + lr * HDIM + quad * 8);
  qf[1] = *(const bf16x8*)(qp + lr * HDIM + 32 + quad * 8);

  const f32x4 fz = {0.f, 0.f, 0.f, 0.f};
  f32x4 oa[4] = {fz, fz, fz, fz};
  f32x4 rsv = fz;
  const int fA = lr & 7;

  for (int ci = 0; ci < 9; ++ci) {
    const int c = ci * 64;
#pragma unroll
    for (int j = 0; j < 2; ++j) {
      int row = (wv * 2 + j) * 8 + subrow;
      gload16(kbh + ((size_t)(c + row)) * HDIM + gsw * 8,
              &Ks[((wv * 2 + j) * 64 + lane) * 8]);
      gload16(vbh + (size_t)row * SEQ + c + gsw * 8,
              &Vs[((wv * 2 + j) * 64 + lane) * 8]);
    }
    __syncthreads();                       // staging visible (+ ms on ci=0)
    f32x4 s[4] = {fz, fz, fz, fz};
#pragma unroll
    for (int ks = 0; ks < 2; ++ks)
#pragma unroll
      for (int t = 0; t < 4; ++t) {
        bf16x8 kf = *(const bf16x8*)(&Ks[(t * 16 + lr) * 64 + (((ks * 4 + quad) ^ fA) * 8)]);
        s[t] = __builtin_amdgcn_mfma_f32_16x16x32_bf16(kf, qf[ks], s[t], 0, 0, 0);
      }
    unsigned int pk0[4], pk1[4];
#pragma unroll
    for (int t = 0; t < 4; ++t) {
      float4 mv = *(const float4*)(&ms[c + t * 16 + quad * 4]);
      s[t][0] = __expf(s[t][0] * 0.125f + mv.x);
      s[t][1] = __expf(s[t][1] * 0.125f + mv.y);
      s[t][2] = __expf(s[t][2] * 0.125f + mv.z);
      s[t][3] = __expf(s[t][3] * 0.125f + mv.w);
      rsv += s[t];
      pk0[t] = pk2(s[t][0], s[t][1]);
      pk1[t] = pk2(s[t][2], s[t][3]);
    }
#pragma unroll
    for (int ks = 0; ks < 2; ++ks) {
      union { unsigned int u[4]; bf16x8 v; } ap;
      ap.u[0] = pk0[ks * 2];     ap.u[1] = pk1[ks * 2];
      ap.u[2] = pk0[ks * 2 + 1]; ap.u[3] = pk1[ks * 2 + 1];
#pragma unroll
      for (int n = 0; n < 4; ++n) {
        bf16x8 vf = *(const bf16x8*)(&Vs[(n * 16 + lr) * 64 + (((ks * 4 + quad) ^ fA) * 8)]);
        oa[n] = __builtin_amdgcn_mfma_f32_16x16x32_bf16(ap.v, vf, oa[n], 0, 0, 0);
      }
    }
    __syncthreads();                       // reads done before next staging
  }

  float rl = rsv[0] + rsv[1] + rsv[2] + rsv[3];
  rl += __shfl_xor(rl, 16);
  rl += __shfl_xor(rl, 32);
  float inv = 1.0f / rl;
  float invr[4];
#pragma unroll
  for (int r = 0; r < 4; ++r) invr[r] = __shfl(inv, quad * 4 + r);

  // epilogue scratch aliases Ks/Vs (all reads drained at final barrier)
  u16* pw = (wv < 2) ? &Ks[wv * 2048] : &Vs[(wv - 2) * 2048];
#pragma unroll
  for (int n = 0; n < 4; ++n)
#pragma unroll
    for (int r = 0; r < 4; ++r)
      pw[(quad * 4 + r) * 68 + n * 16 + lr] = f2bf(oa[n][r] * invr[r]);
  const int token0 = b * SEQ + q0;
  u16* cb = ctxh + ((size_t)h * MTOT + token0) * HDIM;
#pragma unroll
  for (int i = 0; i < 2; ++i) {
    int row = lane & 15;
    int seg = (lane >> 4) + i * 4;
    bf16x8 v8 = *(const bf16x8*)(&pw[row * 68 + seg * 8]);
    *(bf16x8*)(cb + (size_t)row * HDIM + seg * 8) = v8;
  }
}

// ---------------------------------------------------------------------------
// Kernel 3: output projection + bias + residual (R10-measured: 32x128 tile,
// grid 1152, BK=64 single-buffer staging). f32 y, direct stores.
// ---------------------------------------------------------------------------
__global__ __launch_bounds__(256) void out_gemm_k(
    const u16* __restrict__ ctxh, const u16* __restrict__ wto,
    const float* __restrict__ bo,
    const float* __restrict__ word, const float* __restrict__ ent,
    float* __restrict__ y)
{
  __shared__ u16 sh[10240];            // 20480 B: As 32x64 | Bs 128x64
  u16* As = sh;                        // 2048 u16
  u16* Bs = sh + 2048;                 // 8192 u16
  const int m0 = blockIdx.x * 32, n0 = blockIdx.y * 128;
  const int tid = threadIdx.x, lane = tid & 63, wv = tid >> 6;
  const int lr = lane & 15, quad = lane >> 4;
  const int wn = wv * 32;
  const int subrow = lane >> 3;
  const int gsw = ((lane & 7) ^ subrow) * 8;
  const int fsw = lr & 7;

  const f32x4 fz = {0.f, 0.f, 0.f, 0.f};
  f32x4 acc[2][2];
#pragma unroll
  for (int mi = 0; mi < 2; ++mi)
#pragma unroll
    for (int ni = 0; ni < 2; ++ni) acc[mi][ni] = fz;

  for (int hb = 0; hb < 16; ++hb) {            // k0 = hb*64
    {
      int row = wv * 8 + subrow;               // A: 32 rows, 1 slot/wave
      gload16(ctxh + ((size_t)hb * MTOT + (m0 + row)) * HDIM + gsw,
              As + (wv * 64 + lane) * 8);
    }
#pragma unroll
    for (int j = 0; j < 4; ++j) {              // B: 128 rows, 4 slots/wave
      int row = (wv * 4 + j) * 8 + subrow;
      gload16(wto + (size_t)(n0 + row) * HID + hb * 64 + gsw,
              Bs + ((wv * 4 + j) * 64 + lane) * 8);
    }
    __syncthreads();
#pragma unroll
    for (int ks = 0; ks < 2; ++ks) {
      const int kc = (((ks * 4 + quad) ^ fsw) * 8);
      bf16x8 af[2], bfr[2];
#pragma unroll
      for (int i = 0; i < 2; ++i) {
        af[i]  = *(const bf16x8*)(&As[(i * 16 + lr) * 64 + kc]);
        bfr[i] = *(const bf16x8*)(&Bs[(wn + i * 16 + lr) * 64 + kc]);
      }
#pragma unroll
      for (int mi = 0; mi < 2; ++mi)
#pragma unroll
        for (int ni = 0; ni < 2; ++ni)
          acc[mi][ni] = __builtin_amdgcn_mfma_f32_16x16x32_bf16(af[mi], bfr[ni], acc[mi][ni], 0, 0, 0);
    }
    __syncthreads();
  }

#pragma unroll
  for (int mi = 0; mi < 2; ++mi) {
    int rowb = m0 + mi * 16 + quad * 4;
#pragma unroll
    for (int r = 0; r < 4; ++r) {
      int row = rowb + r;
      int bb = row / SEQ, ss = row - bb * SEQ;
      const float* res = (ss < LW) ? (word + (size_t)(bb * LW + ss) * HID)
                                   : (ent  + (size_t)(bb * LE + (ss - LW)) * HID);
#pragma unroll
      for (int ni = 0; ni < 2; ++ni) {
        int col = n0 + wn + ni * 16 + lr;
        y[(size_t)row * HID + col] = acc[mi][ni][r] + bo[col] + res[col];
      }
    }
  }
}

// ---------------------------------------------------------------------------
// Kernel 4: LayerNorm per token + scatter into word|entity output split (f32)
// ---------------------------------------------------------------------------
__global__ __launch_bounds__(256) void ln_k(
    const float* __restrict__ y, const float* __restrict__ lnw,
    const float* __restrict__ lnb, float* __restrict__ out)
{
  const int row = blockIdx.x;
  const int tid = threadIdx.x;
  __shared__ float ssum[4], sqq[4];

  const float* yr = y + (size_t)row * HID;
  float4 v = *(const float4*)(yr + tid * 4);
  float s = v.x + v.y + v.z + v.w;
  float q = v.x * v.x + v.y * v.y + v.z * v.z + v.w * v.w;
#pragma unroll
  for (int o = 32; o > 0; o >>= 1) { s += __shfl_xor(s, o); q += __shfl_xor(q, o); }
  if ((tid & 63) == 0) { ssum[tid >> 6] = s; sqq[tid >> 6] = q; }
  __syncthreads();
  s = ssum[0] + ssum[1] + ssum[2] + ssum[3];
  q = sqq[0] + sqq[1] + sqq[2] + sqq[3];
  float mean = s * (1.0f / HID);
  float var  = q * (1.0f / HID) - mean * mean;
  float rstd = rsqrtf(var + 1e-12f);

  int bb = row / SEQ, ss2 = row - bb * SEQ;
  float* dst = (ss2 < LW)
             ? out + (size_t)(bb * LW + ss2) * HID
             : out + (size_t)BATCH * LW * HID + (size_t)(bb * LE + (ss2 - LW)) * HID;

  float4 w4 = *(const float4*)(lnw + tid * 4);
  float4 b4 = *(const float4*)(lnb + tid * 4);
  float4 o4;
  o4.x = w4.x * (v.x - mean) * rstd + b4.x;
  o4.y = w4.y * (v.y - mean) * rstd + b4.y;
  o4.z = w4.z * (v.z - mean) * rstd + b4.z;
  o4.w = w4.w * (v.w - mean) * rstd + b4.w;
  *(float4*)(dst + tid * 4) = o4;
}

// ---------------------------------------------------------------------------
extern "C" void kernel_launch(void* const* d_in, const int* in_sizes, int n_in,
                              void* d_out, int out_size, void* d_ws, size_t ws_size,
                              hipStream_t stream) {
  const float* word = (const float*)d_in[0];
  const float* ent  = (const float*)d_in[1];
  const float* mask = (const float*)d_in[2];
  const float* Wq   = (const float*)d_in[3];
  const float* bq   = (const float*)d_in[4];
  const float* Wk   = (const float*)d_in[5];
  const float* bk   = (const float*)d_in[6];
  const float* Wv   = (const float*)d_in[7];
  const float* bv   = (const float*)d_in[8];
  const float* Wo   = (const float*)d_in[9];
  const float* bo   = (const float*)d_in[10];
  const float* lnw  = (const float*)d_in[11];
  const float* lnb  = (const float*)d_in[12];

  char* base = (char*)d_ws;
  u16*   wt   = (u16*)base;                               // 8 MB
  u16*   q_ws = (u16*)(base + (size_t)8 * 1024 * 1024);   // 9.44 MB each
  u16*   k_ws = q_ws + (size_t)MTOT * HID;
  u16*   v_ws = k_ws + (size_t)MTOT * HID;
  u16*   ctxh = v_ws + (size_t)MTOT * HID;                // [h][M][64]
  char*  xy   = (char*)(ctxh + (size_t)MTOT * HID);
  u16*   xb   = (u16*)xy;                                 // aliases y (disjoint life)
  float* y    = (float*)xy;

  hipLaunchKernelGGL(prep_k, dim3(4096 + MTOT), dim3(256), 0, stream,
                     Wq, Wk, Wv, Wo, wt, word, ent, xb);
  hipLaunchKernelGGL(qkv_gemm_k, dim3(MTOT / 256, HID / 256, 3), dim3(512), 0, stream,
                     xb, wt, bq, bk, bv, q_ws, k_ws, v_ws);
  hipLaunchKernelGGL(attn_k, dim3(BATCH * NHEADS, SEQ / 64), dim3(256), 0, stream,
                     q_ws, k_ws, v_ws, mask, ctxh);
  hipLaunchKernelGGL(out_gemm_k, dim3(MTOT / 32, HID / 128), dim3(256), 0, stream,
                     ctxh, wt + (size_t)3 * HID * HID, bo, word, ent, y);
  hipLaunchKernelGGL(ln_k, dim3(MTOT), dim3(256), 0, stream,
                     y, lnw, lnb, (float*)d_out);
}

// Round 2
// 200.923 us; speedup vs baseline: 1.1559x; 1.1559x over previous
//
#include <hip/hip_runtime.h>

#define NHEADS 16
#define HDIM   64
#define HID    1024
#define BATCH  8
#define LW     512
#define LE     64
#define SEQ    576            // LW + LE
#define MTOT   (BATCH * SEQ)  // 4608

typedef unsigned short u16;
typedef __bf16 bf16x8 __attribute__((ext_vector_type(8)));
typedef float  f32x4  __attribute__((ext_vector_type(4)));

__device__ __forceinline__ u16 f2bf(float f) {
  union { float f; unsigned int i; } x;
  x.f = f;
  unsigned int u = x.i;
  unsigned int r = (u + 0x7FFFu + ((u >> 16) & 1u)) >> 16;
  return (u16)r;
}
__device__ __forceinline__ unsigned int pk2(float a, float b) {
  return (unsigned int)f2bf(a) | ((unsigned int)f2bf(b) << 16);
}

// async global->LDS, 16B/lane. Per-lane LDS ptr must equal wave base + lane*16.
__device__ __forceinline__ void gload16(const u16* g, u16* l) {
  __builtin_amdgcn_global_load_lds(
      (const __attribute__((address_space(1))) void*)g,
      (__attribute__((address_space(3))) void*)l, 16, 0, 0);
}

// ---------------------------------------------------------------------------
// Kernel 0: prep = weight transpose+cvt (blocks 0..4095) | x gather+cvt (rest)
// ---------------------------------------------------------------------------
__global__ __launch_bounds__(256) void prep_k(
    const float* __restrict__ w0, const float* __restrict__ w1,
    const float* __restrict__ w2, const float* __restrict__ w3,
    u16* __restrict__ wt,
    const float* __restrict__ word, const float* __restrict__ ent,
    u16* __restrict__ xb)
{
  const int bid = blockIdx.x, tid = threadIdx.x;
  if (bid < 4096) {
    __shared__ u16 tile[32][33];
    const int z = bid >> 10, rem = bid & 1023;
    const int bx = rem & 31, by = rem >> 5;
    const float* src = (z == 0) ? w0 : (z == 1) ? w1 : (z == 2) ? w2 : w3;
    u16* dst = wt + (size_t)z * HID * HID;
    const int tx = tid & 31, ty = tid >> 5;
    const int nx = bx * 32, ky = by * 32;
#pragma unroll
    for (int j = 0; j < 4; ++j)
      tile[ty * 4 + j][tx] = f2bf(src[(size_t)(ky + ty * 4 + j) * HID + nx + tx]);
    __syncthreads();
#pragma unroll
    for (int j = 0; j < 4; ++j)
      dst[(size_t)(nx + ty * 4 + j) * HID + ky + tx] = tile[tx][ty * 4 + j];
  } else {
    const int row = bid - 4096;
    const int bb = row / SEQ, ss = row - bb * SEQ;
    const float* src = (ss < LW) ? word + (size_t)(bb * LW + ss) * HID
                                 : ent  + (size_t)(bb * LE + (ss - LW)) * HID;
    float4 v = *(const float4*)(src + tid * 4);
    ushort4 o;
    o.x = f2bf(v.x); o.y = f2bf(v.y); o.z = f2bf(v.z); o.w = f2bf(v.w);
    *(ushort4*)(xb + (size_t)row * HID + tid * 4) = o;
  }
}

// ---------------------------------------------------------------------------
// Kernel 1: fused QKV GEMM — R12: BM=256 BN=128 BK=64, 512 thr = 8 waves
// (4M x 2N), per-wave 64x64 (acc 64 AGPR -> fits the hard 256-reg/wave cap
// that R11's 128x64/wave tile blew, causing scratch spills). 96 KiB LDS dbuf.
// 2 phases/kstep, counted vmcnt(4) (T3+T4) + setprio (T5) + XOR swizzle (T2).
//   ph1: read afr(8)+bfr01(4); stage B(s+1)->obo  [obo fully consumed: safe]
//   ph2: read bfr23(4);        stage A(s+2)->bo   [A(s) reads done at ph1]
//   ph2 end: vmcnt(4) -> A(s+1),B(s+1) arrived; A(s+2) stays in flight.
// Epilogues: R10-proven per-wave 64x64 transpose paths verbatim.
// ---------------------------------------------------------------------------
__global__ __launch_bounds__(512, 2) void qkv_gemm_k(
    const u16* __restrict__ xb, const u16* __restrict__ wt,
    const float* __restrict__ bq, const float* __restrict__ bk, const float* __restrict__ bv,
    u16* __restrict__ q_ws, u16* __restrict__ k_ws, u16* __restrict__ v_ws)
{
  __shared__ u16 sh[49152];            // 96 KiB: 2 x (A 256x64 | B 128x64)
  const int which = blockIdx.z;
  const u16* W = wt + (size_t)which * HID * HID;
  const float* bias = (which == 0) ? bq : (which == 1) ? bk : bv;
  const int m0 = blockIdx.x * 256, n0 = blockIdx.y * 128;
  const int tid = threadIdx.x, lane = tid & 63, wv = tid >> 6;
  const int lr = lane & 15, quad = lane >> 4;
  const int wm = (wv >> 1) * 64, wn = (wv & 1) * 64;   // per-wave 64x64
  const int fsw = lr & 7;

  // staging: all 512 threads cover one 64x64 chunk (row = tid>>3, swizzled k)
  const int srow = tid >> 3;
  const int goff = ((tid & 7) ^ (srow & 7)) * 8;
  const u16* asrc = xb + (size_t)(m0 + srow) * HID + goff;
  const u16* bsrc = W  + (size_t)(n0 + srow) * HID + goff;
  const int ldst = tid * 8;            // u16 offset of this thread's 16B slot

  // prologue: A(0)[4]+B(0)[2] -> buf0 ; A(1)[4] -> buf1 ; wait first 6
  gload16(asrc + (size_t)0 * 64 * HID, sh + 0 * 4096 + ldst);
  gload16(asrc + (size_t)1 * 64 * HID, sh + 1 * 4096 + ldst);
  gload16(asrc + (size_t)2 * 64 * HID, sh + 2 * 4096 + ldst);
  gload16(asrc + (size_t)3 * 64 * HID, sh + 3 * 4096 + ldst);
  gload16(bsrc + (size_t)0 * 64 * HID, sh + 16384 + 0 * 4096 + ldst);
  gload16(bsrc + (size_t)1 * 64 * HID, sh + 16384 + 1 * 4096 + ldst);
  gload16(asrc + (size_t)0 * 64 * HID + 64, sh + 24576 + 0 * 4096 + ldst);
  gload16(asrc + (size_t)1 * 64 * HID + 64, sh + 24576 + 1 * 4096 + ldst);
  gload16(asrc + (size_t)2 * 64 * HID + 64, sh + 24576 + 2 * 4096 + ldst);
  gload16(asrc + (size_t)3 * 64 * HID + 64, sh + 24576 + 3 * 4096 + ldst);
  asm volatile("s_waitcnt vmcnt(4)" ::: "memory");
  __builtin_amdgcn_s_barrier();

  const f32x4 fz = {0.f, 0.f, 0.f, 0.f};
  f32x4 acc[4][4];
#pragma unroll
  for (int a = 0; a < 4; ++a)
#pragma unroll
    for (int b = 0; b < 4; ++b) acc[a][b] = fz;

  for (int s = 0; s < 16; ++s) {
    const int bo  = (s & 1) * 24576;
    const int obo = 24576 - bo;
    u16* As = sh + bo;
    u16* Bs = sh + bo + 16384;

    // ---- phase 1: read A + B(ni 0,1); stage B(s+1) -> obo ----
    bf16x8 afr[4][2], bfr[4][2];
#pragma unroll
    for (int mi = 0; mi < 4; ++mi)
#pragma unroll
      for (int ks = 0; ks < 2; ++ks)
        afr[mi][ks] = *(const bf16x8*)(&As[(wm + mi * 16 + lr) * 64 + (((ks * 4 + quad) ^ fsw) * 8)]);
#pragma unroll
    for (int ni = 0; ni < 2; ++ni)
#pragma unroll
      for (int ks = 0; ks < 2; ++ks)
        bfr[ni][ks] = *(const bf16x8*)(&Bs[(wn + ni * 16 + lr) * 64 + (((ks * 4 + quad) ^ fsw) * 8)]);
    if (s < 15) {
      gload16(bsrc + (size_t)0 * 64 * HID + (s + 1) * 64, sh + obo + 16384 + 0 * 4096 + ldst);
      gload16(bsrc + (size_t)1 * 64 * HID + (s + 1) * 64, sh + obo + 16384 + 1 * 4096 + ldst);
    }
    asm volatile("s_waitcnt lgkmcnt(8)" ::: "memory");
    __builtin_amdgcn_s_barrier();
    asm volatile("s_waitcnt lgkmcnt(0)" ::: "memory");
    __builtin_amdgcn_sched_barrier(0);
    __builtin_amdgcn_s_setprio(1);
    if (which < 2) {
#pragma unroll
      for (int mi = 0; mi < 4; ++mi)
#pragma unroll
        for (int ni = 0; ni < 2; ++ni)
#pragma unroll
          for (int ks = 0; ks < 2; ++ks)
            acc[ni][mi] = __builtin_amdgcn_mfma_f32_16x16x32_bf16(bfr[ni][ks], afr[mi][ks], acc[ni][mi], 0, 0, 0);
    } else {
#pragma unroll
      for (int mi = 0; mi < 4; ++mi)
#pragma unroll
        for (int ni = 0; ni < 2; ++ni)
#pragma unroll
          for (int ks = 0; ks < 2; ++ks)
            acc[mi][ni] = __builtin_amdgcn_mfma_f32_16x16x32_bf16(afr[mi][ks], bfr[ni][ks], acc[mi][ni], 0, 0, 0);
    }
    __builtin_amdgcn_s_setprio(0);
    __builtin_amdgcn_s_barrier();

    // ---- phase 2: read B(ni 2,3); stage A(s+2) -> bo ----
#pragma unroll
    for (int ni = 2; ni < 4; ++ni)
#pragma unroll
      for (int ks = 0; ks < 2; ++ks)
        bfr[ni][ks] = *(const bf16x8*)(&Bs[(wn + ni * 16 + lr) * 64 + (((ks * 4 + quad) ^ fsw) * 8)]);
    if (s < 14) {
      gload16(asrc + (size_t)0 * 64 * HID + (s + 2) * 64, sh + bo + 0 * 4096 + ldst);
      gload16(asrc + (size_t)1 * 64 * HID + (s + 2) * 64, sh + bo + 1 * 4096 + ldst);
      gload16(asrc + (size_t)2 * 64 * HID + (s + 2) * 64, sh + bo + 2 * 4096 + ldst);
      gload16(asrc + (size_t)3 * 64 * HID + (s + 2) * 64, sh + bo + 3 * 4096 + ldst);
    }
    __builtin_amdgcn_s_barrier();
    asm volatile("s_waitcnt lgkmcnt(0)" ::: "memory");
    __builtin_amdgcn_sched_barrier(0);
    __builtin_amdgcn_s_setprio(1);
    if (which < 2) {
#pragma unroll
      for (int mi = 0; mi < 4; ++mi)
#pragma unroll
        for (int ni = 2; ni < 4; ++ni)
#pragma unroll
          for (int ks = 0; ks < 2; ++ks)
            acc[ni][mi] = __builtin_amdgcn_mfma_f32_16x16x32_bf16(bfr[ni][ks], afr[mi][ks], acc[ni][mi], 0, 0, 0);
    } else {
#pragma unroll
      for (int mi = 0; mi < 4; ++mi)
#pragma unroll
        for (int ni = 2; ni < 4; ++ni)
#pragma unroll
          for (int ks = 0; ks < 2; ++ks)
            acc[mi][ni] = __builtin_amdgcn_mfma_f32_16x16x32_bf16(afr[mi][ks], bfr[ni][ks], acc[mi][ni], 0, 0, 0);
    }
    __builtin_amdgcn_s_setprio(0);
    if (s < 14) asm volatile("s_waitcnt vmcnt(4)" ::: "memory");
    else        asm volatile("s_waitcnt vmcnt(0)" ::: "memory");
    __builtin_amdgcn_s_barrier();
  }

  // epilogue: per-wave 64x64 LDS transpose with packed b64 writes (R10 paths)
  u16* tb = sh + wv * (64 * 68);
  const int head = (n0 + wn) >> 6;
  const int mbase = m0 + wm;                   // 64-aligned; never crosses batch
  const int bb = mbase / SEQ;
  const int ssb = mbase - bb * SEQ;

  if (which < 2) {
    // swapped acc: acc[ni][mi], element r: d = ni*16+quad*4+r, token = mi*16+lr
    float4 bias4[4];
#pragma unroll
    for (int ni = 0; ni < 4; ++ni)
      bias4[ni] = *(const float4*)(bias + n0 + wn + ni * 16 + quad * 4);
#pragma unroll
    for (int mi = 0; mi < 4; ++mi)
#pragma unroll
      for (int ni = 0; ni < 4; ++ni) {
        uint2 w2v;
        w2v.x = pk2(acc[ni][mi][0] + bias4[ni].x, acc[ni][mi][1] + bias4[ni].y);
        w2v.y = pk2(acc[ni][mi][2] + bias4[ni].z, acc[ni][mi][3] + bias4[ni].w);
        *(uint2*)(&tb[(mi * 16 + lr) * 68 + ni * 16 + quad * 4]) = w2v;
      }
    u16* drow = (which == 0 ? q_ws : k_ws)
              + ((size_t)(bb * NHEADS + head) * SEQ + ssb) * HDIM;
#pragma unroll
    for (int i = 0; i < 8; ++i) {
      int rrow = i * 8 + (lane >> 3);
      int seg = lane & 7;
      bf16x8 v8 = *(const bf16x8*)(&tb[rrow * 68 + seg * 8]);
      *(bf16x8*)(drow + (size_t)rrow * HDIM + seg * 8) = v8;
    }
  } else {
    // normal acc: acc[mi][ni], d = ni*16+lr, sigma(token) r-consecutive
    float bcol[4];
#pragma unroll
    for (int ni = 0; ni < 4; ++ni) bcol[ni] = bias[n0 + wn + ni * 16 + lr];
#pragma unroll
    for (int mi = 0; mi < 4; ++mi)
#pragma unroll
      for (int ni = 0; ni < 4; ++ni) {
        uint2 w2v;
        w2v.x = pk2(acc[mi][ni][0] + bcol[ni], acc[mi][ni][1] + bcol[ni]);
        w2v.y = pk2(acc[mi][ni][2] + bcol[ni], acc[mi][ni][3] + bcol[ni]);
        *(uint2*)(&tb[(ni * 16 + lr) * 68 + (mi >> 1) * 32 + quad * 8 + (mi & 1) * 4]) = w2v;
      }
    u16* dcol = v_ws + ((size_t)(bb * NHEADS + head) * HDIM) * SEQ + ssb;
#pragma unroll
    for (int i = 0; i < 8; ++i) {
      int d = i * 8 + (lane >> 3);
      int seg = lane & 7;
      bf16x8 v8 = *(const bf16x8*)(&tb[d * 68 + seg * 8]);
      *(bf16x8*)(dcol + (size_t)d * SEQ + seg * 8) = v8;
    }
  }
}

// ---------------------------------------------------------------------------
// Kernel 2: flash attention (R10-measured: single-buffer staging, 18.7 KB LDS)
// ---------------------------------------------------------------------------
__global__ __launch_bounds__(256) void attn_k(
    const u16* __restrict__ q_ws, const u16* __restrict__ k_ws,
    const u16* __restrict__ v_ws, const float* __restrict__ mask,
    u16* __restrict__ ctxh)
{
  __shared__ u16 Ks[4096];
  __shared__ u16 Vs[4096];
  __shared__ float ms[576];
  const int bhx = blockIdx.x, qt = blockIdx.y;
  const int b = bhx >> 4, h = bhx & 15;
  const int tid = threadIdx.x, lane = tid & 63, wv = tid >> 6;
  const int lr = lane & 15, quad = lane >> 4;
  const int q0 = qt * 64 + wv * 16;
  const u16* kbh = k_ws + (size_t)bhx * SEQ * HDIM;
  const u16* vbh = v_ws + (size_t)bhx * HDIM * SEQ;
  const u16* qp  = q_ws + ((size_t)bhx * SEQ + q0) * HDIM;
  const float* mrow = mask + b * SEQ;

  if (tid < 144) *(float4*)(&ms[tid * 4]) = *(const float4*)(mrow + tid * 4);

  const int subrow = lane >> 3;
  const int gsw = (lane & 7) ^ subrow;

  bf16x8 qf[2];
  qf[0] = *(const bf16x8*)(qp + lr * HDIM + quad * 8);
  qf[1] = *(const bf16x8*)(qp + lr * HDIM + 32 + quad * 8);

  const f32x4 fz = {0.f, 0.f, 0.f, 0.f};
  f32x4 oa[4] = {fz, fz, fz, fz};
  f32x4 rsv = fz;
  const int fA = lr & 7;

  for (int ci = 0; ci < 9; ++ci) {
    const int c = ci * 64;
#pragma unroll
    for (int j = 0; j < 2; ++j) {
      int row = (wv * 2 + j) * 8 + subrow;
      gload16(kbh + ((size_t)(c + row)) * HDIM + gsw * 8,
              &Ks[((wv * 2 + j) * 64 + lane) * 8]);
      gload16(vbh + (size_t)row * SEQ + c + gsw * 8,
              &Vs[((wv * 2 + j) * 64 + lane) * 8]);
    }
    __syncthreads();                       // staging visible (+ ms on ci=0)
    f32x4 s[4] = {fz, fz, fz, fz};
#pragma unroll
    for (int ks = 0; ks < 2; ++ks)
#pragma unroll
      for (int t = 0; t < 4; ++t) {
        bf16x8 kf = *(const bf16x8*)(&Ks[(t * 16 + lr) * 64 + (((ks * 4 + quad) ^ fA) * 8)]);
        s[t] = __builtin_amdgcn_mfma_f32_16x16x32_bf16(kf, qf[ks], s[t], 0, 0, 0);
      }
    unsigned int pk0[4], pk1[4];
#pragma unroll
    for (int t = 0; t < 4; ++t) {
      float4 mv = *(const float4*)(&ms[c + t * 16 + quad * 4]);
      s[t][0] = __expf(s[t][0] * 0.125f + mv.x);
      s[t][1] = __expf(s[t][1] * 0.125f + mv.y);
      s[t][2] = __expf(s[t][2] * 0.125f + mv.z);
      s[t][3] = __expf(s[t][3] * 0.125f + mv.w);
      rsv += s[t];
      pk0[t] = pk2(s[t][0], s[t][1]);
      pk1[t] = pk2(s[t][2], s[t][3]);
    }
#pragma unroll
    for (int ks = 0; ks < 2; ++ks) {
      union { unsigned int u[4]; bf16x8 v; } ap;
      ap.u[0] = pk0[ks * 2];     ap.u[1] = pk1[ks * 2];
      ap.u[2] = pk0[ks * 2 + 1]; ap.u[3] = pk1[ks * 2 + 1];
#pragma unroll
      for (int n = 0; n < 4; ++n) {
        bf16x8 vf = *(const bf16x8*)(&Vs[(n * 16 + lr) * 64 + (((ks * 4 + quad) ^ fA) * 8)]);
        oa[n] = __builtin_amdgcn_mfma_f32_16x16x32_bf16(ap.v, vf, oa[n], 0, 0, 0);
      }
    }
    __syncthreads();                       // reads done before next staging
  }

  float rl = rsv[0] + rsv[1] + rsv[2] + rsv[3];
  rl += __shfl_xor(rl, 16);
  rl += __shfl_xor(rl, 32);
  float inv = 1.0f / rl;
  float invr[4];
#pragma unroll
  for (int r = 0; r < 4; ++r) invr[r] = __shfl(inv, quad * 4 + r);

  // epilogue scratch aliases Ks/Vs (all reads drained at final barrier)
  u16* pw = (wv < 2) ? &Ks[wv * 2048] : &Vs[(wv - 2) * 2048];
#pragma unroll
  for (int n = 0; n < 4; ++n)
#pragma unroll
    for (int r = 0; r < 4; ++r)
      pw[(quad * 4 + r) * 68 + n * 16 + lr] = f2bf(oa[n][r] * invr[r]);
  const int token0 = b * SEQ + q0;
  u16* cb = ctxh + ((size_t)h * MTOT + token0) * HDIM;
#pragma unroll
  for (int i = 0; i < 2; ++i) {
    int row = lane & 15;
    int seg = (lane >> 4) + i * 4;
    bf16x8 v8 = *(const bf16x8*)(&pw[row * 68 + seg * 8]);
    *(bf16x8*)(cb + (size_t)row * HDIM + seg * 8) = v8;
  }
}

// ---------------------------------------------------------------------------
// Kernel 3: output projection + bias + residual (R10-measured: 32x128 tile,
// grid 1152, BK=64 single-buffer staging). f32 y, direct stores.
// ---------------------------------------------------------------------------
__global__ __launch_bounds__(256) void out_gemm_k(
    const u16* __restrict__ ctxh, const u16* __restrict__ wto,
    const float* __restrict__ bo,
    const float* __restrict__ word, const float* __restrict__ ent,
    float* __restrict__ y)
{
  __shared__ u16 sh[10240];            // 20480 B: As 32x64 | Bs 128x64
  u16* As = sh;                        // 2048 u16
  u16* Bs = sh + 2048;                 // 8192 u16
  const int m0 = blockIdx.x * 32, n0 = blockIdx.y * 128;
  const int tid = threadIdx.x, lane = tid & 63, wv = tid >> 6;
  const int lr = lane & 15, quad = lane >> 4;
  const int wn = wv * 32;
  const int subrow = lane >> 3;
  const int gsw = ((lane & 7) ^ subrow) * 8;
  const int fsw = lr & 7;

  const f32x4 fz = {0.f, 0.f, 0.f, 0.f};
  f32x4 acc[2][2];
#pragma unroll
  for (int mi = 0; mi < 2; ++mi)
#pragma unroll
    for (int ni = 0; ni < 2; ++ni) acc[mi][ni] = fz;

  for (int hb = 0; hb < 16; ++hb) {            // k0 = hb*64
    {
      int row = wv * 8 + subrow;               // A: 32 rows, 1 slot/wave
      gload16(ctxh + ((size_t)hb * MTOT + (m0 + row)) * HDIM + gsw,
              As + (wv * 64 + lane) * 8);
    }
#pragma unroll
    for (int j = 0; j < 4; ++j) {              // B: 128 rows, 4 slots/wave
      int row = (wv * 4 + j) * 8 + subrow;
      gload16(wto + (size_t)(n0 + row) * HID + hb * 64 + gsw,
              Bs + ((wv * 4 + j) * 64 + lane) * 8);
    }
    __syncthreads();
#pragma unroll
    for (int ks = 0; ks < 2; ++ks) {
      const int kc = (((ks * 4 + quad) ^ fsw) * 8);
      bf16x8 af[2], bfr[2];
#pragma unroll
      for (int i = 0; i < 2; ++i) {
        af[i]  = *(const bf16x8*)(&As[(i * 16 + lr) * 64 + kc]);
        bfr[i] = *(const bf16x8*)(&Bs[(wn + i * 16 + lr) * 64 + kc]);
      }
#pragma unroll
      for (int mi = 0; mi < 2; ++mi)
#pragma unroll
        for (int ni = 0; ni < 2; ++ni)
          acc[mi][ni] = __builtin_amdgcn_mfma_f32_16x16x32_bf16(af[mi], bfr[ni], acc[mi][ni], 0, 0, 0);
    }
    __syncthreads();
  }

#pragma unroll
  for (int mi = 0; mi < 2; ++mi) {
    int rowb = m0 + mi * 16 + quad * 4;
#pragma unroll
    for (int r = 0; r < 4; ++r) {
      int row = rowb + r;
      int bb = row / SEQ, ss = row - bb * SEQ;
      const float* res = (ss < LW) ? (word + (size_t)(bb * LW + ss) * HID)
                                   : (ent  + (size_t)(bb * LE + (ss - LW)) * HID);
#pragma unroll
      for (int ni = 0; ni < 2; ++ni) {
        int col = n0 + wn + ni * 16 + lr;
        y[(size_t)row * HID + col] = acc[mi][ni][r] + bo[col] + res[col];
      }
    }
  }
}

// ---------------------------------------------------------------------------
// Kernel 4: LayerNorm per token + scatter into word|entity output split (f32)
// ---------------------------------------------------------------------------
__global__ __launch_bounds__(256) void ln_k(
    const float* __restrict__ y, const float* __restrict__ lnw,
    const float* __restrict__ lnb, float* __restrict__ out)
{
  const int row = blockIdx.x;
  const int tid = threadIdx.x;
  __shared__ float ssum[4], sqq[4];

  const float* yr = y + (size_t)row * HID;
  float4 v = *(const float4*)(yr + tid * 4);
  float s = v.x + v.y + v.z + v.w;
  float q = v.x * v.x + v.y * v.y + v.z * v.z + v.w * v.w;
#pragma unroll
  for (int o = 32; o > 0; o >>= 1) { s += __shfl_xor(s, o); q += __shfl_xor(q, o); }
  if ((tid & 63) == 0) { ssum[tid >> 6] = s; sqq[tid >> 6] = q; }
  __syncthreads();
  s = ssum[0] + ssum[1] + ssum[2] + ssum[3];
  q = sqq[0] + sqq[1] + sqq[2] + sqq[3];
  float mean = s * (1.0f / HID);
  float var  = q * (1.0f / HID) - mean * mean;
  float rstd = rsqrtf(var + 1e-12f);

  int bb = row / SEQ, ss2 = row - bb * SEQ;
  float* dst = (ss2 < LW)
             ? out + (size_t)(bb * LW + ss2) * HID
             : out + (size_t)BATCH * LW * HID + (size_t)(bb * LE + (ss2 - LW)) * HID;

  float4 w4 = *(const float4*)(lnw + tid * 4);
  float4 b4 = *(const float4*)(lnb + tid * 4);
  float4 o4;
  o4.x = w4.x * (v.x - mean) * rstd + b4.x;
  o4.y = w4.y * (v.y - mean) * rstd + b4.y;
  o4.z = w4.z * (v.z - mean) * rstd + b4.z;
  o4.w = w4.w * (v.w - mean) * rstd + b4.w;
  *(float4*)(dst + tid * 4) = o4;
}

// ---------------------------------------------------------------------------
extern "C" void kernel_launch(void* const* d_in, const int* in_sizes, int n_in,
                              void* d_out, int out_size, void* d_ws, size_t ws_size,
                              hipStream_t stream) {
  const float* word = (const float*)d_in[0];
  const float* ent  = (const float*)d_in[1];
  const float* mask = (const float*)d_in[2];
  const float* Wq   = (const float*)d_in[3];
  const float* bq   = (const float*)d_in[4];
  const float* Wk   = (const float*)d_in[5];
  const float* bk   = (const float*)d_in[6];
  const float* Wv   = (const float*)d_in[7];
  const float* bv   = (const float*)d_in[8];
  const float* Wo   = (const float*)d_in[9];
  const float* bo   = (const float*)d_in[10];
  const float* lnw  = (const float*)d_in[11];
  const float* lnb  = (const float*)d_in[12];

  char* base = (char*)d_ws;
  u16*   wt   = (u16*)base;                               // 8 MB
  u16*   q_ws = (u16*)(base + (size_t)8 * 1024 * 1024);   // 9.44 MB each
  u16*   k_ws = q_ws + (size_t)MTOT * HID;
  u16*   v_ws = k_ws + (size_t)MTOT * HID;
  u16*   ctxh = v_ws + (size_t)MTOT * HID;                // [h][M][64]
  char*  xy   = (char*)(ctxh + (size_t)MTOT * HID);
  u16*   xb   = (u16*)xy;                                 // aliases y (disjoint life)
  float* y    = (float*)xy;

  hipLaunchKernelGGL(prep_k, dim3(4096 + MTOT), dim3(256), 0, stream,
                     Wq, Wk, Wv, Wo, wt, word, ent, xb);
  hipLaunchKernelGGL(qkv_gemm_k, dim3(MTOT / 256, HID / 128, 3), dim3(512), 0, stream,
                     xb, wt, bq, bk, bv, q_ws, k_ws, v_ws);
  hipLaunchKernelGGL(attn_k, dim3(BATCH * NHEADS, SEQ / 64), dim3(256), 0, stream,
                     q_ws, k_ws, v_ws, mask, ctxh);
  hipLaunchKernelGGL(out_gemm_k, dim3(MTOT / 32, HID / 128), dim3(256), 0, stream,
                     ctxh, wt + (size_t)3 * HID * HID, bo, word, ent, y);
  hipLaunchKernelGGL(ln_k, dim3(MTOT), dim3(256), 0, stream,
                     y, lnw, lnb, (float*)d_out);
}

// Round 3
// 197.081 us; speedup vs baseline: 1.1785x; 1.0195x over previous
//
#include <hip/hip_runtime.h>

#define NHEADS 16
#define HDIM   64
#define HID    1024
#define BATCH  8
#define LW     512
#define LE     64
#define SEQ    576            // LW + LE
#define MTOT   (BATCH * SEQ)  // 4608

typedef unsigned short u16;
typedef __bf16 bf16x8 __attribute__((ext_vector_type(8)));
typedef float  f32x4  __attribute__((ext_vector_type(4)));

__device__ __forceinline__ u16 f2bf(float f) {
  union { float f; unsigned int i; } x;
  x.f = f;
  unsigned int u = x.i;
  unsigned int r = (u + 0x7FFFu + ((u >> 16) & 1u)) >> 16;
  return (u16)r;
}
__device__ __forceinline__ unsigned int pk2(float a, float b) {
  return (unsigned int)f2bf(a) | ((unsigned int)f2bf(b) << 16);
}

// async global->LDS, 16B/lane. Per-lane LDS ptr must equal wave base + lane*16.
__device__ __forceinline__ void gload16(const u16* g, u16* l) {
  __builtin_amdgcn_global_load_lds(
      (const __attribute__((address_space(1))) void*)g,
      (__attribute__((address_space(3))) void*)l, 16, 0, 0);
}

// ---------------------------------------------------------------------------
// Kernel 0: prep = weight transpose+cvt (blocks 0..4095) | x gather+cvt (rest)
// ---------------------------------------------------------------------------
__global__ __launch_bounds__(256) void prep_k(
    const float* __restrict__ w0, const float* __restrict__ w1,
    const float* __restrict__ w2, const float* __restrict__ w3,
    u16* __restrict__ wt,
    const float* __restrict__ word, const float* __restrict__ ent,
    u16* __restrict__ xb)
{
  const int bid = blockIdx.x, tid = threadIdx.x;
  if (bid < 4096) {
    __shared__ u16 tile[32][33];
    const int z = bid >> 10, rem = bid & 1023;
    const int bx = rem & 31, by = rem >> 5;
    const float* src = (z == 0) ? w0 : (z == 1) ? w1 : (z == 2) ? w2 : w3;
    u16* dst = wt + (size_t)z * HID * HID;
    const int tx = tid & 31, ty = tid >> 5;
    const int nx = bx * 32, ky = by * 32;
#pragma unroll
    for (int j = 0; j < 4; ++j)
      tile[ty * 4 + j][tx] = f2bf(src[(size_t)(ky + ty * 4 + j) * HID + nx + tx]);
    __syncthreads();
#pragma unroll
    for (int j = 0; j < 4; ++j)
      dst[(size_t)(nx + ty * 4 + j) * HID + ky + tx] = tile[tx][ty * 4 + j];
  } else {
    const int row = bid - 4096;
    const int bb = row / SEQ, ss = row - bb * SEQ;
    const float* src = (ss < LW) ? word + (size_t)(bb * LW + ss) * HID
                                 : ent  + (size_t)(bb * LE + (ss - LW)) * HID;
    float4 v = *(const float4*)(src + tid * 4);
    ushort4 o;
    o.x = f2bf(v.x); o.y = f2bf(v.y); o.z = f2bf(v.z); o.w = f2bf(v.w);
    *(ushort4*)(xb + (size_t)row * HID + tid * 4) = o;
  }
}

// ---------------------------------------------------------------------------
// Kernel 1: fused QKV GEMM — R13: m201-faithful 256x256 tile, BK=64, 512 thr
// = 8 waves (2M x 4N), per-wave 128x64 (acc = 128 AGPR). 128 KiB LDS dbuf.
// 4 phases per K-tile, quadrant order q00->q01->q11->q10 so peak fragment
// liveness = 16 bf16x8 (64 arch VGPR); arch total must stay <= ~128 so
// 128 AGPR + arch fits the 256/wave residency cap (R11 lesson).
// Counted vmcnt(8) ONCE per K-tile (T3+T4); setprio around MFMA (T5);
// XOR-swizzled staging/reads (T2). Chunk-granular WAR schedule:
//   ph1: ds af0(8)+bfL(4)                      [A0,A2,B* reads of tile s]
//   ph2: ds bfH(4);  stage A0,A2(s+2)          [af0 chunks consumed at ph1]
//   ph3: ds af1(8);  stage B0..B3(s+2)         [B chunks consumed at ph2]
//   ph4: (no ds)     stage A1,A3(s+2); vmcnt(8)[af1 chunks consumed at ph3]
// Every phase: barrier; lgkmcnt(0); sched_barrier; prio1; 16 MFMA; prio0; barrier.
// Epilogues: R10-proven per-wave 64x64 transpose paths, two groups (g=0,1).
// ---------------------------------------------------------------------------
#define Q_MFMA(AF, BF, H, NB)                                                 \
  if (which < 2) {                                                            \
    _Pragma("unroll")                                                         \
    for (int mi = 0; mi < 4; ++mi)                                            \
      _Pragma("unroll")                                                       \
      for (int nj = 0; nj < 2; ++nj)                                          \
        _Pragma("unroll")                                                     \
        for (int ks = 0; ks < 2; ++ks)                                        \
          acc[(H)*4 + (NB) + nj][mi] = __builtin_amdgcn_mfma_f32_16x16x32_bf16( \
              BF[nj][ks], AF[mi][ks], acc[(H)*4 + (NB) + nj][mi], 0, 0, 0);   \
  } else {                                                                    \
    _Pragma("unroll")                                                         \
    for (int mi = 0; mi < 4; ++mi)                                            \
      _Pragma("unroll")                                                       \
      for (int nj = 0; nj < 2; ++nj)                                          \
        _Pragma("unroll")                                                     \
        for (int ks = 0; ks < 2; ++ks)                                        \
          acc[(H)*4 + mi][(NB) + nj] = __builtin_amdgcn_mfma_f32_16x16x32_bf16( \
              AF[mi][ks], BF[nj][ks], acc[(H)*4 + mi][(NB) + nj], 0, 0, 0);   \
  }

__global__ __launch_bounds__(512, 2) void qkv_gemm_k(
    const u16* __restrict__ xb, const u16* __restrict__ wt,
    const float* __restrict__ bq, const float* __restrict__ bk, const float* __restrict__ bv,
    u16* __restrict__ q_ws, u16* __restrict__ k_ws, u16* __restrict__ v_ws)
{
  __shared__ u16 sh[65536];            // 128 KiB: 2 x (A 256x64 | B 256x64)
  const int which = blockIdx.z;
  const u16* W = wt + (size_t)which * HID * HID;
  const float* bias = (which == 0) ? bq : (which == 1) ? bk : bv;
  const int m0 = blockIdx.x * 256, n0 = blockIdx.y * 256;
  const int tid = threadIdx.x, lane = tid & 63, wv = tid >> 6;
  const int lr = lane & 15, quad = lane >> 4;
  const int wm = (wv >> 2) * 128, wn = (wv & 3) * 64;   // per-wave 128x64
  const int fsw = lr & 7;
  const int k0o = ((quad ^ fsw)) * 8;          // ks=0 swizzled k-offset (u16)
  const int k1o = (((4 + quad) ^ fsw)) * 8;    // ks=1
  const int aCh = (wv >> 2) * 8192;            // A chunk base for m-half 0 (u16)
  const int bCh = (wv & 3) * 4096;             // B chunk base (u16, rel to Bs)
  const int arow = lr * 64;

  // staging: all 512 threads cover one 64x64 chunk (row = tid>>3, swizzled k)
  const int srow = tid >> 3;
  const int goff = ((tid & 7) ^ (srow & 7)) * 8;
  const u16* asrc = xb + (size_t)(m0 + srow) * HID + goff;
  const u16* bsrc = W  + (size_t)(n0 + srow) * HID + goff;
  const int ldst = tid * 8;            // u16 offset of this thread's 16B slot

  // prologue: T0 (8 chunks) -> buf0, T1 (8 chunks) -> buf1, wait T0
#pragma unroll
  for (int c = 0; c < 4; ++c)
    gload16(asrc + (size_t)c * 64 * HID, sh + c * 4096 + ldst);
#pragma unroll
  for (int c = 0; c < 4; ++c)
    gload16(bsrc + (size_t)c * 64 * HID, sh + 16384 + c * 4096 + ldst);
#pragma unroll
  for (int c = 0; c < 4; ++c)
    gload16(asrc + (size_t)c * 64 * HID + 64, sh + 32768 + c * 4096 + ldst);
#pragma unroll
  for (int c = 0; c < 4; ++c)
    gload16(bsrc + (size_t)c * 64 * HID + 64, sh + 32768 + 16384 + c * 4096 + ldst);
  asm volatile("s_waitcnt vmcnt(8)" ::: "memory");
  __builtin_amdgcn_s_barrier();

  const f32x4 fz = {0.f, 0.f, 0.f, 0.f};
  f32x4 acc[8][4];
#pragma unroll
  for (int a = 0; a < 8; ++a)
#pragma unroll
    for (int b = 0; b < 4; ++b) acc[a][b] = fz;

  for (int s = 0; s < 16; ++s) {
    const int bo = (s & 1) << 15;       // u16: 0 | 32768
    u16* As = sh + bo;
    u16* Bs = sh + bo + 16384;
    const int sOff = (s + 2) * 64;
    const bool gpre = (s < 14);

    bf16x8 af[4][2], bfL[2][2], bfH[2][2];

    // ---- ph1: ds af0 (A m-half0, 8) + bfL (B nfrag 0-1, 4) ; MFMA q00 ----
#pragma unroll
    for (int mi = 0; mi < 4; ++mi) {
      af[mi][0] = *(const bf16x8*)(&As[aCh + mi * 1024 + arow + k0o]);
      af[mi][1] = *(const bf16x8*)(&As[aCh + mi * 1024 + arow + k1o]);
    }
#pragma unroll
    for (int nj = 0; nj < 2; ++nj) {
      bfL[nj][0] = *(const bf16x8*)(&Bs[bCh + nj * 1024 + arow + k0o]);
      bfL[nj][1] = *(const bf16x8*)(&Bs[bCh + nj * 1024 + arow + k1o]);
    }
    asm volatile("s_waitcnt lgkmcnt(8)" ::: "memory");
    __builtin_amdgcn_s_barrier();
    asm volatile("s_waitcnt lgkmcnt(0)" ::: "memory");
    __builtin_amdgcn_sched_barrier(0);
    __builtin_amdgcn_s_setprio(1);
    Q_MFMA(af, bfL, 0, 0)
    __builtin_amdgcn_s_setprio(0);
    __builtin_amdgcn_s_barrier();

    // ---- ph2: ds bfH (B nfrag 2-3, 4); stage A0,A2(s+2); MFMA q01 ----
#pragma unroll
    for (int nj = 0; nj < 2; ++nj) {
      bfH[nj][0] = *(const bf16x8*)(&Bs[bCh + (2 + nj) * 1024 + arow + k0o]);
      bfH[nj][1] = *(const bf16x8*)(&Bs[bCh + (2 + nj) * 1024 + arow + k1o]);
    }
    if (gpre) {
      gload16(asrc + (size_t)0 * 64 * HID + sOff, sh + bo + 0 * 4096 + ldst);
      gload16(asrc + (size_t)2 * 64 * HID + sOff, sh + bo + 2 * 4096 + ldst);
    }
    __builtin_amdgcn_s_barrier();
    asm volatile("s_waitcnt lgkmcnt(0)" ::: "memory");
    __builtin_amdgcn_sched_barrier(0);
    __builtin_amdgcn_s_setprio(1);
    Q_MFMA(af, bfH, 0, 2)
    __builtin_amdgcn_s_setprio(0);
    __builtin_amdgcn_s_barrier();

    // ---- ph3: ds af1 (A m-half1, 8); stage B0..B3(s+2); MFMA q11 ----
#pragma unroll
    for (int mi = 0; mi < 4; ++mi) {
      af[mi][0] = *(const bf16x8*)(&As[aCh + 4096 + mi * 1024 + arow + k0o]);
      af[mi][1] = *(const bf16x8*)(&As[aCh + 4096 + mi * 1024 + arow + k1o]);
    }
    if (gpre) {
      gload16(bsrc + (size_t)0 * 64 * HID + sOff, sh + bo + 16384 + 0 * 4096 + ldst);
      gload16(bsrc + (size_t)1 * 64 * HID + sOff, sh + bo + 16384 + 1 * 4096 + ldst);
      gload16(bsrc + (size_t)2 * 64 * HID + sOff, sh + bo + 16384 + 2 * 4096 + ldst);
      gload16(bsrc + (size_t)3 * 64 * HID + sOff, sh + bo + 16384 + 3 * 4096 + ldst);
    }
    __builtin_amdgcn_s_barrier();
    asm volatile("s_waitcnt lgkmcnt(0)" ::: "memory");
    __builtin_amdgcn_sched_barrier(0);
    __builtin_amdgcn_s_setprio(1);
    Q_MFMA(af, bfH, 1, 2)
    __builtin_amdgcn_s_setprio(0);
    __builtin_amdgcn_s_barrier();

    // ---- ph4: stage A1,A3(s+2); MFMA q10 (af1 x bfL, no ds reads) ----
    if (gpre) {
      gload16(asrc + (size_t)1 * 64 * HID + sOff, sh + bo + 1 * 4096 + ldst);
      gload16(asrc + (size_t)3 * 64 * HID + sOff, sh + bo + 3 * 4096 + ldst);
    }
    __builtin_amdgcn_s_barrier();
    __builtin_amdgcn_sched_barrier(0);
    __builtin_amdgcn_s_setprio(1);
    Q_MFMA(af, bfL, 1, 0)
    __builtin_amdgcn_s_setprio(0);
    if (s < 14)       asm volatile("s_waitcnt vmcnt(8)" ::: "memory");
    else if (s == 14) asm volatile("s_waitcnt vmcnt(0)" ::: "memory");
    __builtin_amdgcn_s_barrier();
  }

  // epilogue: per-wave 64x64 LDS transpose x2 groups, packed b64 writes
  u16* tb = sh + wv * (64 * 68);
  const int head = (n0 + wn) >> 6;

  if (which < 2) {
    // swapped acc: acc[g*4+ni][mi], d = ni*16+quad*4+r, token = mi*16+lr
    float4 bias4[4];
#pragma unroll
    for (int ni = 0; ni < 4; ++ni)
      bias4[ni] = *(const float4*)(bias + n0 + wn + ni * 16 + quad * 4);
    u16* qk = (which == 0 ? q_ws : k_ws);
#pragma unroll
    for (int g = 0; g < 2; ++g) {
      const int mbase = m0 + wm + g * 64;      // 64-aligned; never crosses batch
      const int bb = mbase / SEQ;
      const int ssb = mbase - bb * SEQ;
#pragma unroll
      for (int mi = 0; mi < 4; ++mi)
#pragma unroll
        for (int ni = 0; ni < 4; ++ni) {
          const f32x4 a = acc[g * 4 + ni][mi];
          uint2 w2v;
          w2v.x = pk2(a[0] + bias4[ni].x, a[1] + bias4[ni].y);
          w2v.y = pk2(a[2] + bias4[ni].z, a[3] + bias4[ni].w);
          *(uint2*)(&tb[(mi * 16 + lr) * 68 + ni * 16 + quad * 4]) = w2v;
        }
      u16* drow = qk + ((size_t)(bb * NHEADS + head) * SEQ + ssb) * HDIM;
#pragma unroll
      for (int i = 0; i < 8; ++i) {
        int rrow = i * 8 + (lane >> 3);
        int seg = lane & 7;
        bf16x8 v8 = *(const bf16x8*)(&tb[rrow * 68 + seg * 8]);
        *(bf16x8*)(drow + (size_t)rrow * HDIM + seg * 8) = v8;
      }
    }
  } else {
    // normal acc: acc[g*4+mi][ni], d = ni*16+lr, sigma(token) r-consecutive
    float bcol[4];
#pragma unroll
    for (int ni = 0; ni < 4; ++ni) bcol[ni] = bias[n0 + wn + ni * 16 + lr];
#pragma unroll
    for (int g = 0; g < 2; ++g) {
      const int mbase = m0 + wm + g * 64;
      const int bb = mbase / SEQ;
      const int ssb = mbase - bb * SEQ;
#pragma unroll
      for (int mi = 0; mi < 4; ++mi)
#pragma unroll
        for (int ni = 0; ni < 4; ++ni) {
          const f32x4 a = acc[g * 4 + mi][ni];
          uint2 w2v;
          w2v.x = pk2(a[0] + bcol[ni], a[1] + bcol[ni]);
          w2v.y = pk2(a[2] + bcol[ni], a[3] + bcol[ni]);
          *(uint2*)(&tb[(ni * 16 + lr) * 68 + (mi >> 1) * 32 + quad * 8 + (mi & 1) * 4]) = w2v;
        }
      u16* dcol = v_ws + ((size_t)(bb * NHEADS + head) * HDIM) * SEQ + ssb;
#pragma unroll
      for (int i = 0; i < 8; ++i) {
        int d = i * 8 + (lane >> 3);
        int seg = lane & 7;
        bf16x8 v8 = *(const bf16x8*)(&tb[d * 68 + seg * 8]);
        *(bf16x8*)(dcol + (size_t)d * SEQ + seg * 8) = v8;
      }
    }
  }
}

// ---------------------------------------------------------------------------
// Kernel 2: flash attention (R10-measured: single-buffer staging, 18.7 KB LDS)
// ---------------------------------------------------------------------------
__global__ __launch_bounds__(256) void attn_k(
    const u16* __restrict__ q_ws, const u16* __restrict__ k_ws,
    const u16* __restrict__ v_ws, const float* __restrict__ mask,
    u16* __restrict__ ctxh)
{
  __shared__ u16 Ks[4096];
  __shared__ u16 Vs[4096];
  __shared__ float ms[576];
  const int bhx = blockIdx.x, qt = blockIdx.y;
  const int b = bhx >> 4, h = bhx & 15;
  const int tid = threadIdx.x, lane = tid & 63, wv = tid >> 6;
  const int lr = lane & 15, quad = lane >> 4;
  const int q0 = qt * 64 + wv * 16;
  const u16* kbh = k_ws + (size_t)bhx * SEQ * HDIM;
  const u16* vbh = v_ws + (size_t)bhx * HDIM * SEQ;
  const u16* qp  = q_ws + ((size_t)bhx * SEQ + q0) * HDIM;
  const float* mrow = mask + b * SEQ;

  if (tid < 144) *(float4*)(&ms[tid * 4]) = *(const float4*)(mrow + tid * 4);

  const int subrow = lane >> 3;
  const int gsw = (lane & 7) ^ subrow;

  bf16x8 qf[2];
  qf[0] = *(const bf16x8*)(qp + lr * HDIM + quad * 8);
  qf[1] = *(const bf16x8*)(qp + lr * HDIM + 32 + quad * 8);

  const f32x4 fz = {0.f, 0.f, 0.f, 0.f};
  f32x4 oa[4] = {fz, fz, fz, fz};
  f32x4 rsv = fz;
  const int fA = lr & 7;

  for (int ci = 0; ci < 9; ++ci) {
    const int c = ci * 64;
#pragma unroll
    for (int j = 0; j < 2; ++j) {
      int row = (wv * 2 + j) * 8 + subrow;
      gload16(kbh + ((size_t)(c + row)) * HDIM + gsw * 8,
              &Ks[((wv * 2 + j) * 64 + lane) * 8]);
      gload16(vbh + (size_t)row * SEQ + c + gsw * 8,
              &Vs[((wv * 2 + j) * 64 + lane) * 8]);
    }
    __syncthreads();                       // staging visible (+ ms on ci=0)
    f32x4 s[4] = {fz, fz, fz, fz};
#pragma unroll
    for (int ks = 0; ks < 2; ++ks)
#pragma unroll
      for (int t = 0; t < 4; ++t) {
        bf16x8 kf = *(const bf16x8*)(&Ks[(t * 16 + lr) * 64 + (((ks * 4 + quad) ^ fA) * 8)]);
        s[t] = __builtin_amdgcn_mfma_f32_16x16x32_bf16(kf, qf[ks], s[t], 0, 0, 0);
      }
    unsigned int pk0[4], pk1[4];
#pragma unroll
    for (int t = 0; t < 4; ++t) {
      float4 mv = *(const float4*)(&ms[c + t * 16 + quad * 4]);
      s[t][0] = __expf(s[t][0] * 0.125f + mv.x);
      s[t][1] = __expf(s[t][1] * 0.125f + mv.y);
      s[t][2] = __expf(s[t][2] * 0.125f + mv.z);
      s[t][3] = __expf(s[t][3] * 0.125f + mv.w);
      rsv += s[t];
      pk0[t] = pk2(s[t][0], s[t][1]);
      pk1[t] = pk2(s[t][2], s[t][3]);
    }
#pragma unroll
    for (int ks = 0; ks < 2; ++ks) {
      union { unsigned int u[4]; bf16x8 v; } ap;
      ap.u[0] = pk0[ks * 2];     ap.u[1] = pk1[ks * 2];
      ap.u[2] = pk0[ks * 2 + 1]; ap.u[3] = pk1[ks * 2 + 1];
#pragma unroll
      for (int n = 0; n < 4; ++n) {
        bf16x8 vf = *(const bf16x8*)(&Vs[(n * 16 + lr) * 64 + (((ks * 4 + quad) ^ fA) * 8)]);
        oa[n] = __builtin_amdgcn_mfma_f32_16x16x32_bf16(ap.v, vf, oa[n], 0, 0, 0);
      }
    }
    __syncthreads();                       // reads done before next staging
  }

  float rl = rsv[0] + rsv[1] + rsv[2] + rsv[3];
  rl += __shfl_xor(rl, 16);
  rl += __shfl_xor(rl, 32);
  float inv = 1.0f / rl;
  float invr[4];
#pragma unroll
  for (int r = 0; r < 4; ++r) invr[r] = __shfl(inv, quad * 4 + r);

  // epilogue scratch aliases Ks/Vs (all reads drained at final barrier)
  u16* pw = (wv < 2) ? &Ks[wv * 2048] : &Vs[(wv - 2) * 2048];
#pragma unroll
  for (int n = 0; n < 4; ++n)
#pragma unroll
    for (int r = 0; r < 4; ++r)
      pw[(quad * 4 + r) * 68 + n * 16 + lr] = f2bf(oa[n][r] * invr[r]);
  const int token0 = b * SEQ + q0;
  u16* cb = ctxh + ((size_t)h * MTOT + token0) * HDIM;
#pragma unroll
  for (int i = 0; i < 2; ++i) {
    int row = lane & 15;
    int seg = (lane >> 4) + i * 4;
    bf16x8 v8 = *(const bf16x8*)(&pw[row * 68 + seg * 8]);
    *(bf16x8*)(cb + (size_t)row * HDIM + seg * 8) = v8;
  }
}

// ---------------------------------------------------------------------------
// Kernel 3: output projection + bias + residual (R10-measured: 32x128 tile,
// grid 1152, BK=64 single-buffer staging). f32 y, direct stores.
// ---------------------------------------------------------------------------
__global__ __launch_bounds__(256) void out_gemm_k(
    const u16* __restrict__ ctxh, const u16* __restrict__ wto,
    const float* __restrict__ bo,
    const float* __restrict__ word, const float* __restrict__ ent,
    float* __restrict__ y)
{
  __shared__ u16 sh[10240];            // 20480 B: As 32x64 | Bs 128x64
  u16* As = sh;                        // 2048 u16
  u16* Bs = sh + 2048;                 // 8192 u16
  const int m0 = blockIdx.x * 32, n0 = blockIdx.y * 128;
  const int tid = threadIdx.x, lane = tid & 63, wv = tid >> 6;
  const int lr = lane & 15, quad = lane >> 4;
  const int wn = wv * 32;
  const int subrow = lane >> 3;
  const int gsw = ((lane & 7) ^ subrow) * 8;
  const int fsw = lr & 7;

  const f32x4 fz = {0.f, 0.f, 0.f, 0.f};
  f32x4 acc[2][2];
#pragma unroll
  for (int mi = 0; mi < 2; ++mi)
#pragma unroll
    for (int ni = 0; ni < 2; ++ni) acc[mi][ni] = fz;

  for (int hb = 0; hb < 16; ++hb) {            // k0 = hb*64
    {
      int row = wv * 8 + subrow;               // A: 32 rows, 1 slot/wave
      gload16(ctxh + ((size_t)hb * MTOT + (m0 + row)) * HDIM + gsw,
              As + (wv * 64 + lane) * 8);
    }
#pragma unroll
    for (int j = 0; j < 4; ++j) {              // B: 128 rows, 4 slots/wave
      int row = (wv * 4 + j) * 8 + subrow;
      gload16(wto + (size_t)(n0 + row) * HID + hb * 64 + gsw,
              Bs + ((wv * 4 + j) * 64 + lane) * 8);
    }
    __syncthreads();
#pragma unroll
    for (int ks = 0; ks < 2; ++ks) {
      const int kc = (((ks * 4 + quad) ^ fsw) * 8);
      bf16x8 af[2], bfr[2];
#pragma unroll
      for (int i = 0; i < 2; ++i) {
        af[i]  = *(const bf16x8*)(&As[(i * 16 + lr) * 64 + kc]);
        bfr[i] = *(const bf16x8*)(&Bs[(wn + i * 16 + lr) * 64 + kc]);
      }
#pragma unroll
      for (int mi = 0; mi < 2; ++mi)
#pragma unroll
        for (int ni = 0; ni < 2; ++ni)
          acc[mi][ni] = __builtin_amdgcn_mfma_f32_16x16x32_bf16(af[mi], bfr[ni], acc[mi][ni], 0, 0, 0);
    }
    __syncthreads();
  }

#pragma unroll
  for (int mi = 0; mi < 2; ++mi) {
    int rowb = m0 + mi * 16 + quad * 4;
#pragma unroll
    for (int r = 0; r < 4; ++r) {
      int row = rowb + r;
      int bb = row / SEQ, ss = row - bb * SEQ;
      const float* res = (ss < LW) ? (word + (size_t)(bb * LW + ss) * HID)
                                   : (ent  + (size_t)(bb * LE + (ss - LW)) * HID);
#pragma unroll
      for (int ni = 0; ni < 2; ++ni) {
        int col = n0 + wn + ni * 16 + lr;
        y[(size_t)row * HID + col] = acc[mi][ni][r] + bo[col] + res[col];
      }
    }
  }
}

// ---------------------------------------------------------------------------
// Kernel 4: LayerNorm per token + scatter into word|entity output split (f32)
// ---------------------------------------------------------------------------
__global__ __launch_bounds__(256) void ln_k(
    const float* __restrict__ y, const float* __restrict__ lnw,
    const float* __restrict__ lnb, float* __restrict__ out)
{
  const int row = blockIdx.x;
  const int tid = threadIdx.x;
  __shared__ float ssum[4], sqq[4];

  const float* yr = y + (size_t)row * HID;
  float4 v = *(const float4*)(yr + tid * 4);
  float s = v.x + v.y + v.z + v.w;
  float q = v.x * v.x + v.y * v.y + v.z * v.z + v.w * v.w;
#pragma unroll
  for (int o = 32; o > 0; o >>= 1) { s += __shfl_xor(s, o); q += __shfl_xor(q, o); }
  if ((tid & 63) == 0) { ssum[tid >> 6] = s; sqq[tid >> 6] = q; }
  __syncthreads();
  s = ssum[0] + ssum[1] + ssum[2] + ssum[3];
  q = sqq[0] + sqq[1] + sqq[2] + sqq[3];
  float mean = s * (1.0f / HID);
  float var  = q * (1.0f / HID) - mean * mean;
  float rstd = rsqrtf(var + 1e-12f);

  int bb = row / SEQ, ss2 = row - bb * SEQ;
  float* dst = (ss2 < LW)
             ? out + (size_t)(bb * LW + ss2) * HID
             : out + (size_t)BATCH * LW * HID + (size_t)(bb * LE + (ss2 - LW)) * HID;

  float4 w4 = *(const float4*)(lnw + tid * 4);
  float4 b4 = *(const float4*)(lnb + tid * 4);
  float4 o4;
  o4.x = w4.x * (v.x - mean) * rstd + b4.x;
  o4.y = w4.y * (v.y - mean) * rstd + b4.y;
  o4.z = w4.z * (v.z - mean) * rstd + b4.z;
  o4.w = w4.w * (v.w - mean) * rstd + b4.w;
  *(float4*)(dst + tid * 4) = o4;
}

// ---------------------------------------------------------------------------
extern "C" void kernel_launch(void* const* d_in, const int* in_sizes, int n_in,
                              void* d_out, int out_size, void* d_ws, size_t ws_size,
                              hipStream_t stream) {
  const float* word = (const float*)d_in[0];
  const float* ent  = (const float*)d_in[1];
  const float* mask = (const float*)d_in[2];
  const float* Wq   = (const float*)d_in[3];
  const float* bq   = (const float*)d_in[4];
  const float* Wk   = (const float*)d_in[5];
  const float* bk   = (const float*)d_in[6];
  const float* Wv   = (const float*)d_in[7];
  const float* bv   = (const float*)d_in[8];
  const float* Wo   = (const float*)d_in[9];
  const float* bo   = (const float*)d_in[10];
  const float* lnw  = (const float*)d_in[11];
  const float* lnb  = (const float*)d_in[12];

  char* base = (char*)d_ws;
  u16*   wt   = (u16*)base;                               // 8 MB
  u16*   q_ws = (u16*)(base + (size_t)8 * 1024 * 1024);   // 9.44 MB each
  u16*   k_ws = q_ws + (size_t)MTOT * HID;
  u16*   v_ws = k_ws + (size_t)MTOT * HID;
  u16*   ctxh = v_ws + (size_t)MTOT * HID;                // [h][M][64]
  char*  xy   = (char*)(ctxh + (size_t)MTOT * HID);
  u16*   xb   = (u16*)xy;                                 // aliases y (disjoint life)
  float* y    = (float*)xy;

  hipLaunchKernelGGL(prep_k, dim3(4096 + MTOT), dim3(256), 0, stream,
                     Wq, Wk, Wv, Wo, wt, word, ent, xb);
  hipLaunchKernelGGL(qkv_gemm_k, dim3(MTOT / 256, HID / 256, 3), dim3(512), 0, stream,
                     xb, wt, bq, bk, bv, q_ws, k_ws, v_ws);
  hipLaunchKernelGGL(attn_k, dim3(BATCH * NHEADS, SEQ / 64), dim3(256), 0, stream,
                     q_ws, k_ws, v_ws, mask, ctxh);
  hipLaunchKernelGGL(out_gemm_k, dim3(MTOT / 32, HID / 128), dim3(256), 0, stream,
                     ctxh, wt + (size_t)3 * HID * HID, bo, word, ent, y);
  hipLaunchKernelGGL(ln_k, dim3(MTOT), dim3(256), 0, stream,
                     y, lnw, lnb, (float*)d_out);
}